// Round 1
// baseline (144.224 us; speedup 1.0000x reference)
//
#include <hip/hip_runtime.h>

// Problem: B=8, T=2048, C=1024, H=64
// ref: k=x@Wk^T, q=x@Wq^T, v=x@Wv^T; wei[t,s]=k[t]·q[s]/32, causal s<=t,
//      softmax over s; out[t]=sum_s wei[t,s] v[s].
// Strategy: kernel1 projects x -> bf16 Kp,Qp (row-major [B*T][64]) and
// Vt (transposed [B][64][2048]) in d_ws. kernel2 = flash attention with
// 16x16x32 bf16 MFMA, online softmax, per-wave 16-row q-tiles, KVBLK=64.

typedef __attribute__((ext_vector_type(8))) short short8;   // 8 bf16
typedef __attribute__((ext_vector_type(4))) float f32x4;

#define BATCH 8
#define T 2048
#define CDIM 1024
#define HD 64

static __device__ __forceinline__ short f2bf(float f) {
    unsigned u = __builtin_bit_cast(unsigned, f);
    u += 0x7fffu + ((u >> 16) & 1u);          // RNE
    return (short)(u >> 16);
}

// ---------------- Projection GEMM: M=16384, K=1024, N=64 per proj ----------
// grid: (256 m-tiles, 3 projs), block 256 (4 waves). Tile: 64 rows x 64 cols.
#define LDSP 40   // padded row length (elements); 80B rows -> 16B-aligned, ~2-way banks

__global__ __launch_bounds__(256) void proj_kernel(
    const float* __restrict__ x,
    const float* __restrict__ Wk, const float* __restrict__ Wq,
    const float* __restrict__ Wv,
    short* __restrict__ kp, short* __restrict__ qp, short* __restrict__ vt)
{
    const int mtile = blockIdx.x;
    const int p = blockIdx.y;
    const float* __restrict__ W = (p == 0) ? Wk : (p == 1 ? Wq : Wv);

    __shared__ short xs[64 * LDSP];
    __shared__ short wsh[64 * LDSP];

    const int tid = threadIdx.x;
    const int wid = tid >> 6;
    const int lane = tid & 63;
    const int row = tid >> 2;        // 0..63
    const int slot = tid & 3;        // 0..3 (8 floats each)
    const int m0 = mtile * 64;
    const int g = lane >> 4, c = lane & 15;

    f32x4 acc[4] = {};

    for (int k0 = 0; k0 < CDIM; k0 += 32) {
        const float* xsrc = x + (size_t)(m0 + row) * CDIM + k0 + slot * 8;
        float4 a0 = *(const float4*)xsrc;
        float4 a1 = *(const float4*)(xsrc + 4);
        short8 xv = { f2bf(a0.x), f2bf(a0.y), f2bf(a0.z), f2bf(a0.w),
                      f2bf(a1.x), f2bf(a1.y), f2bf(a1.z), f2bf(a1.w) };
        const float* wsrc = W + (size_t)row * CDIM + k0 + slot * 8;
        float4 b0 = *(const float4*)wsrc;
        float4 b1 = *(const float4*)(wsrc + 4);
        short8 wv = { f2bf(b0.x), f2bf(b0.y), f2bf(b0.z), f2bf(b0.w),
                      f2bf(b1.x), f2bf(b1.y), f2bf(b1.z), f2bf(b1.w) };

        *(short8*)&xs[row * LDSP + slot * 8] = xv;
        *(short8*)&wsh[row * LDSP + slot * 8] = wv;
        __syncthreads();

        short8 af = *(short8*)&xs[(wid * 16 + c) * LDSP + g * 8];
#pragma unroll
        for (int ct = 0; ct < 4; ct++) {
            short8 bf = *(short8*)&wsh[(ct * 16 + c) * LDSP + g * 8];
            acc[ct] = __builtin_amdgcn_mfma_f32_16x16x32_bf16(af, bf, acc[ct], 0, 0, 0);
        }
        __syncthreads();
    }

    // epilogue: C layout col=lane&15, row=(lane>>4)*4+reg
    if (p == 2) {
#pragma unroll
        for (int ct = 0; ct < 4; ct++)
#pragma unroll
            for (int r = 0; r < 4; r++) {
                int grow = m0 + wid * 16 + g * 4 + r;
                int bb = grow >> 11, s = grow & 2047;
                vt[((size_t)(bb * 64 + ct * 16 + c)) * T + s] = f2bf(acc[ct][r]);
            }
    } else {
        short* __restrict__ dst = (p == 0) ? kp : qp;
#pragma unroll
        for (int ct = 0; ct < 4; ct++)
#pragma unroll
            for (int r = 0; r < 4; r++) {
                int grow = m0 + wid * 16 + g * 4 + r;
                dst[(size_t)grow * HD + ct * 16 + c] = f2bf(acc[ct][r]);
            }
    }
}

// ---------------- Flash attention -----------------------------------------
// grid 256 blocks x 256 threads. Each wave owns one 16-row t-tile; the 4
// waves of block (b=bid&7, pg=bid>>3) take tiles {2pg, 2pg+1, 126-2pg,
// 127-2pg} so every block has equal total s-work (causal balance).
__global__ __launch_bounds__(256) void attn_kernel(
    const short* __restrict__ kp, const short* __restrict__ qp,
    const short* __restrict__ vt, float* __restrict__ out)
{
    const int bid = blockIdx.x;
    const int b = bid & 7;
    const int pg = bid >> 3;
    const int tid = threadIdx.x;
    const int wid = tid >> 6;
    const int lane = tid & 63;
    const int g = lane >> 4, c = lane & 15;

    int j = (wid == 0) ? 2 * pg : (wid == 1) ? 2 * pg + 1
          : (wid == 2) ? 126 - 2 * pg : 127 - 2 * pg;
    const int t0 = j * 16;

    __shared__ short p_lds[4][16 * 64];
    char* pl = (char*)(&p_lds[wid][0]);

    const short* __restrict__ kpb = kp + (size_t)b * T * HD;
    const short* __restrict__ qpb = qp + (size_t)b * T * HD;
    const short* __restrict__ vtb = vt + (size_t)b * HD * T;

    // A-frags: K rows of this t-tile (lane: row = c, k-chunk g*8, two k-steps)
    short8 afk0 = *(const short8*)&kpb[(size_t)(t0 + c) * HD + g * 8];
    short8 afk1 = *(const short8*)&kpb[(size_t)(t0 + c) * HD + 32 + g * 8];

    float m_r[4], l_r[4];
    f32x4 o[4] = {};
#pragma unroll
    for (int r = 0; r < 4; r++) { m_r[r] = -1e30f; l_r[r] = 0.f; }

    const int nst = (t0 + 15) / 64 + 1;
    for (int st = 0; st < nst; ++st) {
        const int s0 = st * 64;
        // ---- scores S[16 rows t][64 cols s] ----
        f32x4 s_acc[4] = {};
#pragma unroll
        for (int ct = 0; ct < 4; ct++) {
            short8 bq0 = *(const short8*)&qpb[(size_t)(s0 + ct * 16 + c) * HD + g * 8];
            short8 bq1 = *(const short8*)&qpb[(size_t)(s0 + ct * 16 + c) * HD + 32 + g * 8];
            s_acc[ct] = __builtin_amdgcn_mfma_f32_16x16x32_bf16(afk0, bq0, s_acc[ct], 0, 0, 0);
            s_acc[ct] = __builtin_amdgcn_mfma_f32_16x16x32_bf16(afk1, bq1, s_acc[ct], 0, 0, 0);
        }

        const bool diag = (s0 + 63 > t0);
        float sv[4][4];
#pragma unroll
        for (int ct = 0; ct < 4; ct++)
#pragma unroll
            for (int r = 0; r < 4; r++) {
                float v = s_acc[ct][r] * 0.03125f;
                if (diag) {
                    int s = s0 + ct * 16 + c;
                    int t = t0 + g * 4 + r;
                    if (s > t) v = -1e30f;
                }
                sv[ct][r] = v;
            }

        // ---- online softmax ----
        float mnew[4], alpha[4];
#pragma unroll
        for (int r = 0; r < 4; r++) {
            float mx = fmaxf(fmaxf(sv[0][r], sv[1][r]), fmaxf(sv[2][r], sv[3][r]));
#pragma unroll
            for (int off = 1; off < 16; off <<= 1)
                mx = fmaxf(mx, __shfl_xor(mx, off));
            mnew[r] = fmaxf(m_r[r], mx);
            alpha[r] = __expf(m_r[r] - mnew[r]);
            m_r[r] = mnew[r];
        }

        float rsum[4] = {0.f, 0.f, 0.f, 0.f};
        short pv16[4][4];
#pragma unroll
        for (int ct = 0; ct < 4; ct++)
#pragma unroll
            for (int r = 0; r < 4; r++) {
                float pe = __expf(sv[ct][r] - m_r[r]);
                rsum[r] += pe;
                pv16[ct][r] = f2bf(pe);
            }
#pragma unroll
        for (int r = 0; r < 4; r++) {
#pragma unroll
            for (int off = 1; off < 16; off <<= 1)
                rsum[r] += __shfl_xor(rsum[r], off);
            l_r[r] = l_r[r] * alpha[r] + rsum[r];
        }
#pragma unroll
        for (int dt = 0; dt < 4; dt++)
#pragma unroll
            for (int r = 0; r < 4; r++)
                o[dt][r] *= alpha[r];

        // ---- transpose P via LDS (XOR-swizzled: byte = row*128 + (s*2 ^ ((row&7)<<4))) ----
#pragma unroll
        for (int ct = 0; ct < 4; ct++)
#pragma unroll
            for (int r = 0; r < 4; r++) {
                int prow = g * 4 + r;
                int ps = ct * 16 + c;
                *(short*)(pl + prow * 128 + ((ps * 2) ^ ((prow & 7) << 4))) = pv16[ct][r];
            }

        // ---- PV: O[16 t][64 d] += P[16 t][64 s] * V[64 s][64 d] ----
        short8 pa0 = *(short8*)(pl + c * 128 + (((0 * 32 + g * 8) * 2) ^ ((c & 7) << 4)));
        short8 pa1 = *(short8*)(pl + c * 128 + (((1 * 32 + g * 8) * 2) ^ ((c & 7) << 4)));
#pragma unroll
        for (int dt = 0; dt < 4; dt++) {
            short8 vb0 = *(const short8*)&vtb[(size_t)(dt * 16 + c) * T + s0 + g * 8];
            short8 vb1 = *(const short8*)&vtb[(size_t)(dt * 16 + c) * T + s0 + 32 + g * 8];
            o[dt] = __builtin_amdgcn_mfma_f32_16x16x32_bf16(pa0, vb0, o[dt], 0, 0, 0);
            o[dt] = __builtin_amdgcn_mfma_f32_16x16x32_bf16(pa1, vb1, o[dt], 0, 0, 0);
        }
    }

    // ---- epilogue: out[b][t][d] = O/l ----
#pragma unroll
    for (int dt = 0; dt < 4; dt++)
#pragma unroll
        for (int r = 0; r < 4; r++) {
            int t = t0 + g * 4 + r;
            int d = dt * 16 + c;
            out[((size_t)b * T + t) * HD + d] = o[dt][r] / l_r[r];
        }
}

extern "C" void kernel_launch(void* const* d_in, const int* in_sizes, int n_in,
                              void* d_out, int out_size, void* d_ws, size_t ws_size,
                              hipStream_t stream) {
    const float* x  = (const float*)d_in[0];
    const float* Wk = (const float*)d_in[1];
    const float* Wq = (const float*)d_in[2];
    const float* Wv = (const float*)d_in[3];
    float* out = (float*)d_out;

    short* kp = (short*)d_ws;                       // [8*2048][64] bf16
    short* qp = kp + (size_t)BATCH * T * HD;        // [8*2048][64] bf16
    short* vt = qp + (size_t)BATCH * T * HD;        // [8][64][2048] bf16

    proj_kernel<<<dim3(256, 3), 256, 0, stream>>>(x, Wk, Wq, Wv, kp, qp, vt);
    attn_kernel<<<256, 256, 0, stream>>>(kp, qp, vt, out);
}

// Round 2
// 82.121 us; speedup vs baseline: 1.7562x; 1.7562x over previous
//
#include <hip/hip_runtime.h>
#include <hip/hip_bf16.h>

// B=8, T=2048, C=1024, H=64. ref: wei = (k q^T)/32, causal, softmax, @v.
// k1: proj x->bf16 kp (pre-scaled by log2e/32), qp, vt (V transposed [b][d][s]).
// k2: split-s flash attention, 1-wave blocks, chunks of 4 s-tiles (64 each),
//     partials (m,l,O) to ws.  k3: combine partials -> out.

typedef __attribute__((ext_vector_type(8))) short short8;   // 8 bf16
typedef __attribute__((ext_vector_type(4))) float f32x4;

#define BATCH 8
#define T 2048
#define CDIM 1024
#define HD 64
#define CHUNK 4
#define SLOTS_PER_B 576
#define QK_SCALE 0.04509985873f   // (1/32) * log2(e)  -> softmax in exp2 domain

static __device__ __forceinline__ short f2bf(float f) {
    return __builtin_bit_cast(short, __float2bfloat16(f));   // RNE, packs to v_cvt_pk_bf16_f32
}
static __device__ __forceinline__ f32x4 mfma16(short8 a, short8 b, f32x4 c) {
    return __builtin_amdgcn_mfma_f32_16x16x32_bf16(a, b, c, 0, 0, 0);
}

// ---------------- projection GEMM: 64-row tile x 64 cols, BK=64 -------------
#define LDSP 72   // pitch in shorts (144B): 16B-aligned rows, worst 2-way banks (free)

__global__ __launch_bounds__(256) void proj_kernel(
    const float* __restrict__ x,
    const float* __restrict__ Wk, const float* __restrict__ Wq,
    const float* __restrict__ Wv,
    short* __restrict__ kp, short* __restrict__ qp, short* __restrict__ vt)
{
    const int mtile = blockIdx.x;
    const int p = blockIdx.y;
    const float* __restrict__ W = (p == 0) ? Wk : (p == 1 ? Wq : Wv);

    __shared__ __align__(16) short xs[64 * LDSP];
    __shared__ __align__(16) short wsh[64 * LDSP];

    const int tid = threadIdx.x;
    const int wid = tid >> 6;
    const int lane = tid & 63;
    const int row = tid >> 2;        // 0..63
    const int q4 = tid & 3;          // 16-float column chunk
    const int m0 = mtile * 64;
    const int g = lane >> 4, cc = lane & 15;

    f32x4 acc[4] = {};

    for (int k0 = 0; k0 < CDIM; k0 += 64) {
        const float* xsrc = x + (size_t)(m0 + row) * CDIM + k0 + q4 * 16;
        const float* wsrc = W + (size_t)row * CDIM + k0 + q4 * 16;
        float xr[16], wr[16];
#pragma unroll
        for (int u = 0; u < 4; ++u) {
            f32x4 a = *(const f32x4*)(xsrc + 4 * u);
            f32x4 bb = *(const f32x4*)(wsrc + 4 * u);
#pragma unroll
            for (int e = 0; e < 4; ++e) { xr[4 * u + e] = a[e]; wr[4 * u + e] = bb[e]; }
        }
        short8 xv0, xv1, wv0, wv1;
#pragma unroll
        for (int e = 0; e < 8; ++e) {
            xv0[e] = f2bf(xr[e]);     xv1[e] = f2bf(xr[e + 8]);
            wv0[e] = f2bf(wr[e]);     wv1[e] = f2bf(wr[e + 8]);
        }
        __syncthreads();
        *(short8*)&xs[row * LDSP + q4 * 16] = xv0;
        *(short8*)&xs[row * LDSP + q4 * 16 + 8] = xv1;
        *(short8*)&wsh[row * LDSP + q4 * 16] = wv0;
        *(short8*)&wsh[row * LDSP + q4 * 16 + 8] = wv1;
        __syncthreads();
#pragma unroll
        for (int kk = 0; kk < 2; ++kk) {
            short8 af = *(short8*)&xs[(wid * 16 + cc) * LDSP + kk * 32 + g * 8];
#pragma unroll
            for (int ct = 0; ct < 4; ++ct) {
                short8 bf = *(short8*)&wsh[(ct * 16 + cc) * LDSP + kk * 32 + g * 8];
                acc[ct] = mfma16(af, bf, acc[ct]);
            }
        }
    }

    // ---- epilogue: stage through LDS so every global store is 16B coalesced
    __syncthreads();
    if (p == 2) {   // vt: [b][d][s] layout -> stage transposed [d][t_local]
#pragma unroll
        for (int ct = 0; ct < 4; ++ct)
#pragma unroll
            for (int r = 0; r < 4; ++r)
                xs[(ct * 16 + cc) * LDSP + wid * 16 + g * 4 + r] = f2bf(acc[ct][r]);
    } else {        // kp/qp: [t][d] -> stage [t_local][d]; fold QK scale into kp
        const float sc = (p == 0) ? QK_SCALE : 1.0f;
#pragma unroll
        for (int ct = 0; ct < 4; ++ct)
#pragma unroll
            for (int r = 0; r < 4; ++r)
                xs[(wid * 16 + g * 4 + r) * LDSP + ct * 16 + cc] = f2bf(acc[ct][r] * sc);
    }
    __syncthreads();
    short8 o0 = *(short8*)&xs[row * LDSP + q4 * 16];
    short8 o1 = *(short8*)&xs[row * LDSP + q4 * 16 + 8];
    if (p == 2) {
        const int bb = m0 >> 11, s0 = m0 & 2047;
        short* d = vt + (size_t)(bb * 64 + row) * T + s0 + q4 * 16;
        *(short8*)d = o0; *(short8*)(d + 8) = o1;
    } else {
        short* d = (p == 0 ? kp : qp) + (size_t)(m0 + row) * HD + q4 * 16;
        *(short8*)d = o0; *(short8*)(d + 8) = o1;
    }
}

// ---------------- split-s flash attention (1 wave per block) ----------------
template<bool SPLIT>
__global__ __launch_bounds__(64, 4) void attn_kernel(
    const short* __restrict__ kp, const short* __restrict__ qp,
    const short* __restrict__ vt, float* __restrict__ out,
    float* __restrict__ pO, float* __restrict__ pML)
{
    const int j = blockIdx.x;                 // t-tile (16 rows)
    const int ck = SPLIT ? blockIdx.y : 0;    // chunk index
    const int b = blockIdx.z;
    const int i16 = j >> 4;
    const int nc = i16 + 1;                   // ceil((j/4+1)/CHUNK)
    if (SPLIT && ck >= nc) return;
    const int n = (j >> 2) + 1;               // s-tiles for this t-tile
    const int st0 = SPLIT ? ck * CHUNK : 0;
    const int st1 = SPLIT ? ((st0 + CHUNK < n) ? st0 + CHUNK : n) : n;

    const int lane = threadIdx.x;
    const int g = lane >> 4, c = lane & 15;
    const int t0 = j * 16;

    __shared__ __align__(16) short p_lds[16 * 64];
    char* pl = (char*)p_lds;

    const short* __restrict__ kpb = kp + (size_t)b * T * HD;
    const short* __restrict__ qpb = qp + (size_t)b * T * HD;
    const short* __restrict__ vtb = vt + (size_t)b * HD * T;

    short8 afk0 = *(const short8*)&kpb[(size_t)(t0 + c) * HD + g * 8];
    short8 afk1 = *(const short8*)&kpb[(size_t)(t0 + c) * HD + 32 + g * 8];

    float m_r[4], l_r[4];
    f32x4 o[4] = {};
#pragma unroll
    for (int r = 0; r < 4; ++r) { m_r[r] = -1e30f; l_r[r] = 0.f; }

    for (int st = st0; st < st1; ++st) {
        const int s0 = st * 64;
        f32x4 s_acc[4] = {};
#pragma unroll
        for (int ct = 0; ct < 4; ++ct) {
            short8 bq0 = *(const short8*)&qpb[(size_t)(s0 + ct * 16 + c) * HD + g * 8];
            short8 bq1 = *(const short8*)&qpb[(size_t)(s0 + ct * 16 + c) * HD + 32 + g * 8];
            s_acc[ct] = mfma16(afk0, bq0, s_acc[ct]);
            s_acc[ct] = mfma16(afk1, bq1, s_acc[ct]);
        }

        const bool diag = (s0 + 63 > t0);
        float sv[4][4];
#pragma unroll
        for (int ct = 0; ct < 4; ++ct)
#pragma unroll
            for (int r = 0; r < 4; ++r) {
                float v = s_acc[ct][r];                 // scale pre-folded into kp
                if (diag) {
                    int s = s0 + ct * 16 + c;
                    int t = t0 + g * 4 + r;
                    if (s > t) v = -1e30f;
                }
                sv[ct][r] = v;
            }

        float mnew[4], alpha[4];
#pragma unroll
        for (int r = 0; r < 4; ++r) {
            float mx = fmaxf(fmaxf(sv[0][r], sv[1][r]), fmaxf(sv[2][r], sv[3][r]));
#pragma unroll
            for (int off = 1; off < 16; off <<= 1)
                mx = fmaxf(mx, __shfl_xor(mx, off));
            mnew[r] = fmaxf(m_r[r], mx);
            alpha[r] = exp2f(m_r[r] - mnew[r]);
            m_r[r] = mnew[r];
        }

        float rsum[4] = {0.f, 0.f, 0.f, 0.f};
        short pv16[4][4];
#pragma unroll
        for (int ct = 0; ct < 4; ++ct)
#pragma unroll
            for (int r = 0; r < 4; ++r) {
                float pe = exp2f(sv[ct][r] - m_r[r]);
                rsum[r] += pe;
                pv16[ct][r] = f2bf(pe);
            }
#pragma unroll
        for (int r = 0; r < 4; ++r) {
#pragma unroll
            for (int off = 1; off < 16; off <<= 1)
                rsum[r] += __shfl_xor(rsum[r], off);
            l_r[r] = l_r[r] * alpha[r] + rsum[r];
        }
#pragma unroll
        for (int dt = 0; dt < 4; ++dt)
#pragma unroll
            for (int r = 0; r < 4; ++r)
                o[dt][r] *= alpha[r];

        // transpose P via XOR-swizzled LDS
#pragma unroll
        for (int ct = 0; ct < 4; ++ct)
#pragma unroll
            for (int r = 0; r < 4; ++r) {
                int prow = g * 4 + r;
                int ps = ct * 16 + c;
                *(short*)(pl + prow * 128 + ((ps * 2) ^ ((prow & 7) << 4))) = pv16[ct][r];
            }
        short8 pa0 = *(short8*)(pl + c * 128 + (((g * 8) * 2) ^ ((c & 7) << 4)));
        short8 pa1 = *(short8*)(pl + c * 128 + (((32 + g * 8) * 2) ^ ((c & 7) << 4)));
#pragma unroll
        for (int dt = 0; dt < 4; ++dt) {
            short8 vb0 = *(const short8*)&vtb[(size_t)(dt * 16 + c) * T + s0 + g * 8];
            short8 vb1 = *(const short8*)&vtb[(size_t)(dt * 16 + c) * T + s0 + 32 + g * 8];
            o[dt] = mfma16(pa0, vb0, o[dt]);
            o[dt] = mfma16(pa1, vb1, o[dt]);
        }
    }

    if constexpr (!SPLIT) {
#pragma unroll
        for (int dt = 0; dt < 4; ++dt)
#pragma unroll
            for (int r = 0; r < 4; ++r)
                out[((size_t)b * T + t0 + g * 4 + r) * HD + dt * 16 + c] = o[dt][r] / l_r[r];
    } else {
        const int slot = b * SLOTS_PER_B + 8 * i16 * (i16 + 1) + (j & 15) * nc + ck;
        float* po = pO + (size_t)slot * 1024;
#pragma unroll
        for (int dt = 0; dt < 4; ++dt)
#pragma unroll
            for (int r = 0; r < 4; ++r)
                po[(g * 4 + r) * 64 + dt * 16 + c] = o[dt][r];
        if (c == 0) {
#pragma unroll
            for (int r = 0; r < 4; ++r) {
                pML[slot * 32 + g * 4 + r] = m_r[r];
                pML[slot * 32 + 16 + g * 4 + r] = l_r[r];
            }
        }
    }
}

// ---------------- combine partials ----------------
__global__ __launch_bounds__(256) void combine_kernel(
    const float* __restrict__ pO, const float* __restrict__ pML,
    float* __restrict__ out)
{
    const int j = blockIdx.x, b = blockIdx.y;
    const int i16 = j >> 4, nc = i16 + 1;
    const int base = b * SLOTS_PER_B + 8 * i16 * (i16 + 1) + (j & 15) * nc;
    const int tid = threadIdx.x;
    const int t = tid >> 4, dq = tid & 15;

    float M = -1e30f;
    for (int cq = 0; cq < nc; ++cq)
        M = fmaxf(M, pML[(base + cq) * 32 + t]);
    float L = 0.f;
    f32x4 acc = {};
    for (int cq = 0; cq < nc; ++cq) {
        float w = exp2f(pML[(base + cq) * 32 + t] - M);
        L += w * pML[(base + cq) * 32 + 16 + t];
        f32x4 ov = *(const f32x4*)&pO[(size_t)(base + cq) * 1024 + t * 64 + dq * 4];
#pragma unroll
        for (int e = 0; e < 4; ++e) acc[e] += w * ov[e];
    }
    const float inv = 1.f / L;
    f32x4 res;
#pragma unroll
    for (int e = 0; e < 4; ++e) res[e] = acc[e] * inv;
    *(f32x4*)&out[((size_t)b * T + j * 16 + t) * HD + dq * 4] = res;
}

extern "C" void kernel_launch(void* const* d_in, const int* in_sizes, int n_in,
                              void* d_out, int out_size, void* d_ws, size_t ws_size,
                              hipStream_t stream) {
    const float* x  = (const float*)d_in[0];
    const float* Wk = (const float*)d_in[1];
    const float* Wq = (const float*)d_in[2];
    const float* Wv = (const float*)d_in[3];
    float* out = (float*)d_out;

    short* kp = (short*)d_ws;                       // [8*2048][64] bf16 (pre-scaled)
    short* qp = kp + (size_t)BATCH * T * HD;        // [8*2048][64] bf16
    short* vt = qp + (size_t)BATCH * T * HD;        // [8][64][2048] bf16
    float* pO  = (float*)(vt + (size_t)BATCH * T * HD);          // [4608][16][64]
    float* pML = pO + (size_t)BATCH * SLOTS_PER_B * 1024;        // [4608][32]

    const size_t need = (size_t)BATCH * T * HD * 2 * 3
                      + (size_t)BATCH * SLOTS_PER_B * (1024 + 32) * 4;

    proj_kernel<<<dim3(256, 3), 256, 0, stream>>>(x, Wk, Wq, Wv, kp, qp, vt);
    if (ws_size >= need) {
        attn_kernel<true><<<dim3(128, 8, BATCH), 64, 0, stream>>>(kp, qp, vt, nullptr, pO, pML);
        combine_kernel<<<dim3(128, BATCH), 256, 0, stream>>>(pO, pML, out);
    } else {
        attn_kernel<false><<<dim3(128, 1, BATCH), 64, 0, stream>>>(kp, qp, vt, out, nullptr, nullptr);
    }
}